// Round 10
// baseline (234.010 us; speedup 1.0000x reference)
//
#include <hip/hip_runtime.h>
#include <hip/hip_bf16.h>
#include <stdint.h>

// ---------------------------------------------------------------------------
// CustomConvLayer: out[b,o,h,w] = sum_{c,dh,dw} xpad[b,c,h+dh,w+dw] * W[o,c,dh*3+dw]
// Implicit-im2col GEMM, bf16 MFMA 16x16x32. M=B*H*W, N=128, K=576.
//
// R13: TLP pivot. R10/R11/R12 proved the compiler re-sinks every prefetch
// load (VGPR pinned at 68 through launch-bounds and sched_barrier fences),
// so ILP-based latency hiding is unreachable at source level. The kernel is
// latency-bound with all pipes <30%. Fix occupancy instead: 512-thread
// blocks at the same 49.9KB LDS -> 3 blocks/CU = 24 waves/CU (was 12).
// Each of 8 waves owns a 32x64 output tile (acc[2][4], 32 acc VGPRs; 8 MFMA
// per K-step). Transpose staging remapped to 512 threads: 6 units
// (slab-row x w-half); wave = c-octet; per instruction a wave reads 256B
// contiguous (2x128B segments). Same swizzled Aslab (measured 0 conflicts),
// same fragment math / epilogue shape / xform_w. Compiler may sink loads
// freely -- 24 resident waves do the hiding via TLP, which it cannot defeat.
// ---------------------------------------------------------------------------

typedef __bf16 bf16x8 __attribute__((ext_vector_type(8)));
typedef float  f32x4  __attribute__((ext_vector_type(4)));

// ---------------- weights -> fragment-order BtF[s][quad][n] 16B chunks -------
// chunk(s,quad,n)[r] = W[n][c][tap] with k = s*32+quad*8+r, tap=k>>6, c=k&63
__global__ __launch_bounds__(256) void xform_w(const float* __restrict__ wgt,
                                               __bf16* __restrict__ BtF) {
  const int t = blockIdx.x * 256 + threadIdx.x;  // chunk id
  if (t >= 9216) return;
  const int s = t >> 9, rem = t & 511, quad = rem >> 7, n = rem & 127;
  bf16x8 o;
#pragma unroll
  for (int r = 0; r < 8; ++r) {
    const int k = s * 32 + quad * 8 + r;
    const int tap = k >> 6, c = k & 63;
    o[r] = (__bf16)wgt[(n * 64 + c) * 9 + tap];
  }
  *(bf16x8*)(BtF + (size_t)t * 8) = o;
}

// ---------------- fused conv: block=(b,h), 512 thr / 8 waves -----------------
__global__ __launch_bounds__(512) void conv_mfma(const float* __restrict__ x,
                                                 const __bf16* __restrict__ BtF,
                                                 float* __restrict__ out) {
  __shared__ alignas(16) __bf16 Aslab[3120 * 8];  // 49,920 B: 3 rows x 130 wp x 64 c
  const int tid  = threadIdx.x;
  const int lane = tid & 63;
  const int wave = tid >> 6;          // 0..7
  const int quad = lane >> 4;
  const int l16  = lane & 15;
  // XCD-aware swizzle: same-XCD blocks get contiguous (b,h) -> x-row L2 reuse
  const int rank = (blockIdx.x & 7) * 256 + (blockIdx.x >> 3);
  const int b = rank >> 7;
  const int h = rank & 127;
  const int wn = wave & 1;            // N half (64 cols)
  const int wm = wave >> 1;           // M quarter (32 rows)

  // ---- edge chunks wp=0 / wp=129 -> zeros (48 chunks; ordered by the barrier)
  if (tid < 48) {
    const int r3 = tid >> 4, wp = ((tid >> 3) & 1) * 129, cq = tid & 7;
    const int v = r3 * 130 + wp;
    const bf16x8 z = {};
    *(bf16x8*)(Aslab + (size_t)(v * 8 + (cq ^ (v & 7))) * 8) = z;
  }

  // ---- transpose staging: 6 units (r = t>>1 slab row, wh = t&1 w-half).
  // Wave = c-octet (c8), lane = w offset (wl). Per unit: 8 scalar dword loads
  // (64 lanes -> 256B contiguous, 2x128B segments), cvt in reg, ONE 16B
  // swizzled ds_write (same pattern as R10: measured 0 bank conflicts).
  const int c8 = wave;                // c-octet 0..7
  const int wl = tid & 63;            // 0..63
  const float* xb = x + ((size_t)b * 64 + c8 * 8) * 16384 + wl;  // + cc*16384 + xr*128 + wh*64

#pragma unroll
  for (int t = 0; t < 6; ++t) {
    const int r  = t >> 1;            // slab row 0..2
    const int wh = t & 1;             // w half
    const int xr = h - 1 + r;
    bf16x8 pk = {};
    if (xr >= 0 && xr <= 127) {
      const float* p0 = xb + (size_t)xr * 128 + wh * 64;
      float f[8];
#pragma unroll
      for (int cc = 0; cc < 8; ++cc) f[cc] = p0[(size_t)cc * 16384];
#pragma unroll
      for (int cc = 0; cc < 8; ++cc) pk[cc] = (__bf16)f[cc];
    }
    const int v = r * 130 + 1 + wh * 64 + wl;
    *(bf16x8*)(Aslab + (size_t)(v * 8 + (c8 ^ (v & 7))) * 8) = pk;
  }
  __syncthreads();  // the only barrier

  // ---- 18-step MFMA loop: per wave 2x4 fragments (32x64 tile), 8 MFMA/step
  f32x4 acc[2][4] = {};
#pragma unroll
  for (int s = 0; s < 18; ++s) {
    const int tap = s >> 1;
    const int dh = tap / 3, dw = tap % 3;
    const int cq = ((s & 1) << 2) + quad;  // 16B chunk index within a 64-elem row
    bf16x8 aF[2], bF[4];                   // plain locals, constant-indexed (SROA)
#pragma unroll
    for (int i = 0; i < 2; ++i) {
      const int m = (wm << 5) + (i << 4) + l16;
      const int v = dh * 130 + m + dw;
      const int slot = (v << 3) + (cq ^ (v & 7));
      aF[i] = *(const bf16x8*)(Aslab + (size_t)slot * 8);
    }
#pragma unroll
    for (int j = 0; j < 4; ++j) {
      const int n = (wn << 6) + (j << 4) + l16;
      bF[j] = *(const bf16x8*)(BtF + ((size_t)((s * 4 + quad) * 128 + n) << 3));
    }
#pragma unroll
    for (int i = 0; i < 2; ++i)
#pragma unroll
      for (int j = 0; j < 4; ++j)
        acc[i][j] = __builtin_amdgcn_mfma_f32_16x16x32_bf16(aF[i], bF[j], acc[i][j], 0, 0, 0);
  }

  // epilogue: D col = lane&15 = n, row = quad*4+reg = m (out w). Plain stores.
#pragma unroll
  for (int j = 0; j < 4; ++j) {
    const int n = (wn << 6) + (j << 4) + l16;
    float* orow = out + (((size_t)(b * 128 + n) * 128 + h) << 7);
#pragma unroll
    for (int i = 0; i < 2; ++i) {
      const int m0 = (wm << 5) + (i << 4) + (quad << 2);
      *(f32x4*)(orow + m0) = acc[i][j];  // quads 0..3 tile one 64B line per n
    }
  }
}

// ---------------- fallback (if workspace too small): direct fp32 conv -------
__global__ void conv_naive(const float* __restrict__ x, const float* __restrict__ wgt,
                           float* __restrict__ out, int total) {
  int idx = blockIdx.x * 256 + threadIdx.x;
  if (idx >= total) return;
  const int w = idx & 127;
  const int h = (idx >> 7) & 127;
  const int o = (idx >> 14) & 127;
  const int b = idx >> 21;
  float s = 0.f;
  for (int c = 0; c < 64; ++c) {
    const float* xc = x + ((size_t)(b * 64 + c) * 128) * 128;
    const float* wc = wgt + (o * 64 + c) * 9;
    for (int dh = 0; dh < 3; ++dh) {
      const int hh = h + dh - 1;
      if (hh < 0 || hh >= 128) continue;
      for (int dw = 0; dw < 3; ++dw) {
        const int ww = w + dw - 1;
        if (ww < 0 || ww >= 128) continue;
        s += xc[hh * 128 + ww] * wc[dh * 3 + dw];
      }
    }
  }
  out[idx] = s;
}

extern "C" void kernel_launch(void* const* d_in, const int* in_sizes, int n_in,
                              void* d_out, int out_size, void* d_ws, size_t ws_size,
                              hipStream_t stream) {
  const float* x   = (const float*)d_in[0];
  const float* wgt = (const float*)d_in[1];
  float* out = (float*)d_out;

  const size_t BTF_BYTES = 9216ull * 16;  // 147456 (L2-resident)

  if (ws_size < BTF_BYTES) {
    const int total = 16 * 128 * 128 * 128;
    conv_naive<<<(total + 255) / 256, 256, 0, stream>>>(x, wgt, out, total);
    return;
  }

  __bf16* BtF = (__bf16*)d_ws;

  xform_w<<<36, 256, 0, stream>>>(wgt, BtF);
  conv_mfma<<<2048, 512, 0, stream>>>(x, BtF, out);
}

// Round 11
// 218.064 us; speedup vs baseline: 1.0731x; 1.0731x over previous
//
#include <hip/hip_runtime.h>
#include <hip/hip_bf16.h>
#include <stdint.h>

// ---------------------------------------------------------------------------
// CustomConvLayer: out[b,o,h,w] = sum_{c,dh,dw} xpad[b,c,h+dh,w+dw] * W[o,c,dh*3+dw]
// Implicit-im2col GEMM, bf16 MFMA 16x16x32. M=B*H*W, N=128, K=576.
//
// R14: fused transpose (R10) + LDS-fed bF ring (R7) -- first combination.
// Evidence: every variant with register bF loads in the K-loop lands at
// 85-104us (compiler sinks loads to use: VGPR pinned 68/44 across 3 forcing
// attempts; each step pays a serial L2 round-trip). R13's TLP pivot made it
// worse (more waves, each stalling harder). global_load_lds is fire-and-
// forget (no reg dest) -> unsinkable; counted vmcnt genuinely holds (R7).
// Structure: in-register NCHW transpose prologue (0 conflicts, proven) ->
// issue ring slices S0..S2 -> 18 steps of {vmcnt(N); lgkmcnt(0); s_barrier;
// issue S(s+2); 4 aF + 4 bF ds_reads; 16 MFMA}. Zero in-loop register VMEM:
// per-step critical path becomes LDS (~120cyc) + MFMA, not L2 (~300-600cyc).
// FIFO ledger: waits 4,2x16,0; issues at steps 1..15; slot (s+2)%3's readers
// drained by the previous step's lgkmcnt(0)+barrier. LDS 74.8KB -> 2 blk/CU.
// ---------------------------------------------------------------------------

typedef __bf16 bf16x8 __attribute__((ext_vector_type(8)));
typedef float  f32x4  __attribute__((ext_vector_type(4)));

#define GLD_TO_LDS16(g, l)                                                        \
  __builtin_amdgcn_global_load_lds((const __attribute__((address_space(1))) void*)(g), \
                                   (__attribute__((address_space(3))) void*)(l), 16, 0, 0)

// ---------------- weights -> fragment-order BtF[s][quad][n] 16B chunks -------
// chunk(s,quad,n)[r] = W[n][c][tap] with k = s*32+quad*8+r, tap=k>>6, c=k&63
__global__ __launch_bounds__(256) void xform_w(const float* __restrict__ wgt,
                                               __bf16* __restrict__ BtF) {
  const int t = blockIdx.x * 256 + threadIdx.x;  // chunk id
  if (t >= 9216) return;
  const int s = t >> 9, rem = t & 511, quad = rem >> 7, n = rem & 127;
  bf16x8 o;
#pragma unroll
  for (int r = 0; r < 8; ++r) {
    const int k = s * 32 + quad * 8 + r;
    const int tap = k >> 6, c = k & 63;
    o[r] = (__bf16)wgt[(n * 64 + c) * 9 + tap];
  }
  *(bf16x8*)(BtF + (size_t)t * 8) = o;
}

// ---------------- fused conv: transpose prologue + LDS-fed ring K-loop ------
__global__ __launch_bounds__(256) void conv_mfma(const float* __restrict__ x,
                                                 const __bf16* __restrict__ BtF,
                                                 float* __restrict__ out) {
  // chunks 0..3119: Aslab (3 rows x 130 wp x 64 c, swizzled)
  // chunks 3136..4671: bF ring, 3 slots x 512 chunks, linear
  __shared__ alignas(16) __bf16 Aslab[4672 * 8];  // 74,752 B -> 2 blocks/CU
  const int tid  = threadIdx.x;
  const int lane = tid & 63;
  const int wave = tid >> 6;
  const int quad = lane >> 4;
  const int l16  = lane & 15;
  // XCD-aware swizzle: same-XCD blocks get contiguous (b,h) -> x-row L2 reuse
  const int rank = (blockIdx.x & 7) * 256 + (blockIdx.x >> 3);
  const int b = rank >> 7;
  const int h = rank & 127;
  const int wm = wave >> 1;  // M half
  const int wn = wave & 1;   // N half

  // ---- edge chunks wp=0 / wp=129 -> zeros (48 chunks; ordered by step-0 bar)
  if (tid < 48) {
    const int r3 = tid >> 4, wp = ((tid >> 3) & 1) * 129, cq = tid & 7;
    const int v = r3 * 130 + wp;
    const bf16x8 z = {};
    *(bf16x8*)(Aslab + (size_t)(v * 8 + (cq ^ (v & 7))) * 8) = z;
  }

  // ---- transpose staging: 12 units (u=t>>2 slab row, p=t&3 w-quarter).
  // Thread owns (c8 = tid>>5 c-octet, wl = tid&31). Per unit: 8 coalesced
  // scalar dword loads (lanes along w), cvt in reg, ONE 16B swizzled ds_write.
  const int c8 = tid >> 5;
  const int wl = tid & 31;
  const float* xb = x + ((size_t)b * 64 + c8 * 8) * 16384 + wl;  // + cc*16384 + xr*128 + p*32

  float f[4][8];  // depth-4 ring; constant-indexed under full unroll

#define T_ISSUE(T) do {                                                       \
    const int u_ = (T) >> 2, p_ = (T) & 3;                                    \
    const int xr_ = h - 1 + u_;                                               \
    if (xr_ >= 0 && xr_ <= 127) {                                             \
      const float* p0_ = xb + (size_t)xr_ * 128 + p_ * 32;                    \
      _Pragma("unroll")                                                       \
      for (int cc = 0; cc < 8; ++cc) f[(T) & 3][cc] = p0_[(size_t)cc * 16384];\
    }                                                                         \
  } while (0)

#define T_CONSUME(T) do {                                                     \
    const int u_ = (T) >> 2, p_ = (T) & 3;                                    \
    const int xr_ = h - 1 + u_;                                               \
    bf16x8 pk = {};                                                           \
    if (xr_ >= 0 && xr_ <= 127) {                                             \
      _Pragma("unroll")                                                       \
      for (int cc = 0; cc < 8; ++cc) pk[cc] = (__bf16)f[(T) & 3][cc];         \
    }                                                                         \
    const int v_ = u_ * 130 + 1 + p_ * 32 + wl;                               \
    *(bf16x8*)(Aslab + (size_t)(v_ * 8 + (c8 ^ (v_ & 7))) * 8) = pk;          \
  } while (0)

  T_ISSUE(0); T_ISSUE(1); T_ISSUE(2);
#pragma unroll
  for (int t = 0; t < 12; ++t) {
    if (t < 9) T_ISSUE(t + 3);   // ring slot (t+3)&3 != t&3: safe before consume
    T_CONSUME(t);
  }
  __builtin_amdgcn_sched_barrier(0);  // x-load FIFO drained; ring issues next

  // ---- bF ring: slice K (8KB = BtF chunks K*512..+511) via 2 gload_lds units
  // dst linear at ring slot K%3; per wave per unit = exactly 1 VMEM op.
#define STAGE_S(K, U) do {                                                    \
    GLD_TO_LDS16(BtF + ((size_t)(((K) << 9) + ((U) << 8) + (wave << 6) + lane) << 3), \
                 (char*)Aslab + ((3136 + (((K) % 3) << 9) + ((U) << 8) + (wave << 6)) << 4)); \
  } while (0)

  STAGE_S(0, 0); STAGE_S(0, 1);
  STAGE_S(1, 0); STAGE_S(1, 1);
  STAGE_S(2, 0); STAGE_S(2, 1);
  __builtin_amdgcn_sched_barrier(0);
  // no prologue __syncthreads: step-0's vmcnt(4)+lgkmcnt(0)+barrier covers
  // the ds_writes, edge zeros, and S0 readiness without draining S1/S2.

  f32x4 acc[4][4] = {};

  // step S: dh=S/6, dw=(S%6)/2, half=S&1; bF from ring slot S%3.
#define STEP(S, VM) do {                                                       \
    asm volatile("s_waitcnt vmcnt(" #VM ")" ::: "memory");                     \
    asm volatile("s_waitcnt lgkmcnt(0)" ::: "memory");                         \
    __builtin_amdgcn_s_barrier();                                              \
    __builtin_amdgcn_sched_barrier(0);                                         \
    if ((S) >= 1 && (S) <= 15) { STAGE_S((S) + 2, 0); STAGE_S((S) + 2, 1); }   \
    __builtin_amdgcn_sched_barrier(0);                                         \
    {                                                                          \
      const int dh_ = (S) / 6, dw_ = ((S) % 6) >> 1, half_ = (S) & 1;          \
      const int cq_ = (half_ << 2) + quad;                                     \
      bf16x8 aF[4], bF[4]; /* plain locals, constant-indexed (SROA) */         \
      _Pragma("unroll")                                                        \
      for (int i = 0; i < 4; ++i) {                                            \
        const int m_    = (wm << 6) + (i << 4) + l16;                          \
        const int v_    = dh_ * 130 + m_ + dw_;                                \
        const int slot_ = (v_ << 3) + (cq_ ^ (v_ & 7));                        \
        aF[i] = *(const bf16x8*)(Aslab + (size_t)slot_ * 8);                   \
        bF[i] = *(const bf16x8*)(Aslab +                                       \
            ((size_t)(3136 + (((S) % 3) << 9) + (quad << 7) + (wn << 6) +      \
                      (i << 4) + l16) << 3));                                  \
      }                                                                        \
      _Pragma("unroll")                                                        \
      for (int i = 0; i < 4; ++i)                                              \
        _Pragma("unroll")                                                      \
        for (int j = 0; j < 4; ++j)                                            \
          acc[i][j] = __builtin_amdgcn_mfma_f32_16x16x32_bf16(aF[i], bF[j],    \
                                                              acc[i][j], 0, 0, 0); \
    }                                                                          \
  } while (0)

  // FIFO ledger: prologue leaves {S0,S1,S2}=6 ops. Step0 waits vmcnt(4)->S0.
  // Steps 1..16 wait vmcnt(2) (2 slices in flight); step 17 drains.
  STEP(0, 4);   STEP(1, 2);   STEP(2, 2);
  STEP(3, 2);   STEP(4, 2);   STEP(5, 2);
  STEP(6, 2);   STEP(7, 2);   STEP(8, 2);
  STEP(9, 2);   STEP(10, 2);  STEP(11, 2);
  STEP(12, 2);  STEP(13, 2);  STEP(14, 2);
  STEP(15, 2);  STEP(16, 2);  STEP(17, 0);

  // epilogue: D col = lane&15 = n, row = quad*4+reg = m (out w). Plain stores.
#pragma unroll
  for (int j = 0; j < 4; ++j) {
    const int n = (wn << 6) + (j << 4) + l16;
    float* orow = out + (((size_t)(b * 128 + n) * 128 + h) << 7);
#pragma unroll
    for (int i = 0; i < 4; ++i) {
      const int m0 = (wm << 6) + (i << 4) + (quad << 2);
      *(f32x4*)(orow + m0) = acc[i][j];  // quads 0..3 tile one 64B line per n
    }
  }
}

// ---------------- fallback (if workspace too small): direct fp32 conv -------
__global__ void conv_naive(const float* __restrict__ x, const float* __restrict__ wgt,
                           float* __restrict__ out, int total) {
  int idx = blockIdx.x * 256 + threadIdx.x;
  if (idx >= total) return;
  const int w = idx & 127;
  const int h = (idx >> 7) & 127;
  const int o = (idx >> 14) & 127;
  const int b = idx >> 21;
  float s = 0.f;
  for (int c = 0; c < 64; ++c) {
    const float* xc = x + ((size_t)(b * 64 + c) * 128) * 128;
    const float* wc = wgt + (o * 64 + c) * 9;
    for (int dh = 0; dh < 3; ++dh) {
      const int hh = h + dh - 1;
      if (hh < 0 || hh >= 128) continue;
      for (int dw = 0; dw < 3; ++dw) {
        const int ww = w + dw - 1;
        if (ww < 0 || ww >= 128) continue;
        s += xc[hh * 128 + ww] * wc[dh * 3 + dw];
      }
    }
  }
  out[idx] = s;
}

extern "C" void kernel_launch(void* const* d_in, const int* in_sizes, int n_in,
                              void* d_out, int out_size, void* d_ws, size_t ws_size,
                              hipStream_t stream) {
  const float* x   = (const float*)d_in[0];
  const float* wgt = (const float*)d_in[1];
  float* out = (float*)d_out;

  const size_t BTF_BYTES = 9216ull * 16;  // 147456 (L2-resident)

  if (ws_size < BTF_BYTES) {
    const int total = 16 * 128 * 128 * 128;
    conv_naive<<<(total + 255) / 256, 256, 0, stream>>>(x, wgt, out, total);
    return;
  }

  __bf16* BtF = (__bf16*)d_ws;

  xform_w<<<36, 256, 0, stream>>>(wgt, BtF);
  conv_mfma<<<2048, 256, 0, stream>>>(x, BtF, out);
}